// Round 12
// baseline (6672.149 us; speedup 1.0000x reference)
//
#include <hip/hip_runtime.h>
#include <hip/hip_bf16.h>

typedef short s8v __attribute__((ext_vector_type(8)));
typedef float f4v __attribute__((ext_vector_type(4)));
typedef unsigned int u4v __attribute__((ext_vector_type(4)));
typedef unsigned int u2v __attribute__((ext_vector_type(2)));

#define NBLK 64
#define TPB 384

constexpr int BB = 32, TT = 512, DD = 512, HH = 1024;
constexpr int KK = DD + HH;          // 1536
constexpr int PK = KK + 8;           // padded LDS K-stride
constexpr int PK8 = PK / 8;
constexpr int K8 = KK / 8;

// ---- workspace layout (bytes) ----
constexpr size_t OFF_WGT = 0;
constexpr size_t SZ_WGT  = (size_t)2 * HH * KK * 2;
constexpr size_t OFF_WCT = OFF_WGT + SZ_WGT;
constexpr size_t SZ_WCT  = (size_t)HH * KK * 2;
constexpr size_t OFF_XBF = OFF_WCT + SZ_WCT;
constexpr size_t SZ_XBF  = (size_t)BB * TT * DD * 2;
constexpr size_t OFF_HPB = OFF_XBF + SZ_XBF;                    // h publish (coherent)
constexpr size_t SZ_PUB  = (size_t)BB * HH * 2;
constexpr size_t OFF_RPB = OFF_HPB + SZ_PUB;                    // rh publish (coherent)
constexpr size_t OFF_FLG = OFF_RPB + SZ_PUB;                    // hflag[64*4] + fpair[64*4]
constexpr size_t SZ_FLG  = (size_t)2 * NBLK * 4 * 4;            // 2,048

// ---------------------------------------------------------------------------
__global__ void wtr_kernel(const float* __restrict__ in, unsigned short* __restrict__ out, int N) {
    __shared__ float tl[32][33];
    int tx = threadIdx.x & 31, ty = threadIdx.x >> 5;
    int n0 = blockIdx.x * 32, k0 = blockIdx.y * 32;
#pragma unroll
    for (int r = ty; r < 32; r += 8) tl[r][tx] = in[(size_t)(k0 + r) * N + n0 + tx];
    __syncthreads();
#pragma unroll
    for (int r = ty; r < 32; r += 8) {
        __hip_bfloat16 h = __float2bfloat16(tl[tx][r]);
        out[(size_t)(n0 + r) * KK + k0 + tx] = *reinterpret_cast<unsigned short*>(&h);
    }
}

__global__ void xconv_kernel(const float* __restrict__ X, unsigned short* __restrict__ Xbf) {
    size_t i = ((size_t)blockIdx.x * 256 + threadIdx.x) * 4;
    float4 v = *reinterpret_cast<const float4*>(X + i);
    __hip_bfloat16 h0 = __float2bfloat16(v.x), h1 = __float2bfloat16(v.y);
    __hip_bfloat16 h2 = __float2bfloat16(v.z), h3 = __float2bfloat16(v.w);
    ushort4 o;
    o.x = *(unsigned short*)&h0; o.y = *(unsigned short*)&h1;
    o.z = *(unsigned short*)&h2; o.w = *(unsigned short*)&h3;
    *reinterpret_cast<ushort4*>(Xbf + i) = o;
}

// ---------------------------------------------------------------------------
// Proven coherent primitives: sc0 sc1 (system scope) loads/stores for cross-
// block data; agent-scope atomic loads for flag polls. No fences.
__device__ __forceinline__ u4v cload16(const void* p) {
    u4v r; asm volatile("global_load_dwordx4 %0, %1, off sc0 sc1" : "=v"(r) : "v"(p) : "memory"); return r;
}
__device__ __forceinline__ void cstore8(void* p, u2v v) {
    asm volatile("global_store_dwordx2 %0, %1, off sc0 sc1" :: "v"(p), "v"(v) : "memory");
}
__device__ __forceinline__ void cstore4(void* p, int v) {
    asm volatile("global_store_dword %0, %1, off sc0 sc1" :: "v"(p), "v"(v) : "memory");
}
#define B16(x) __builtin_bit_cast(s8v, (x))
#define WAIT_VM(n) do { asm volatile("s_waitcnt vmcnt(" #n ")" ::: "memory"); \
                        __builtin_amdgcn_sched_barrier(0); } while (0)

// 64 lanes poll 64 per-block flags (one each), padded 16B.
__device__ __forceinline__ void poll1(const int* f, int gen, int lane) {
    const int* fp = f + lane * 4;
    while (__hip_atomic_load(fp, __ATOMIC_RELAXED, __HIP_MEMORY_SCOPE_AGENT) < gen)
        __builtin_amdgcn_s_sleep(1);
    asm volatile("" ::: "memory");
}
// 64 lanes poll {rh, urd} int-pairs (8B) per block.
__device__ __forceinline__ void poll2(const int* f, int gen, int lane) {
    const int* fp = f + lane * 4;
    while (true) {
        u2v v; asm volatile("global_load_dwordx2 %0, %1, off sc0 sc1\ns_waitcnt vmcnt(0)"
                            : "=v"(v) : "v"(fp) : "memory");
        if ((int)v[0] >= gen && (int)v[1] >= gen) break;
        __builtin_amdgcn_s_sleep(1);
    }
    asm volatile("" ::: "memory");
}

// Intra-block LDS handoff flags (off-critical-path; slack >= 1 rendezvous).
__device__ __forceinline__ void lds_spin(volatile int* p, int gen) {
    while (*p < gen) __builtin_amdgcn_s_sleep(1);
    asm volatile("s_waitcnt lgkmcnt(0)" ::: "memory");
    __builtin_amdgcn_sched_barrier(0);
}
__device__ __forceinline__ void lds_set(volatile int* p, int gen, int lane) {
    asm volatile("s_waitcnt lgkmcnt(0)" ::: "memory");
    if (lane == 0) *p = gen;
}

#define MFMA(A, B, C) __builtin_amdgcn_mfma_f32_16x16x32_bf16((A), (B), (C), 0, 0, 0)

// consume 8 k-chunks (base b0) from 8 named regs, round-robin over 4 accums
#define C8(b0, r0, r1, r2, r3, r4, r5, r6, r7) \
    a0 = MFMA(B16(r0), bwh[(b0 + 0) * 4], a0); a1 = MFMA(B16(r1), bwh[(b0 + 1) * 4], a1); \
    a2 = MFMA(B16(r2), bwh[(b0 + 2) * 4], a2); a3 = MFMA(B16(r3), bwh[(b0 + 3) * 4], a3); \
    a0 = MFMA(B16(r4), bwh[(b0 + 4) * 4], a0); a1 = MFMA(B16(r5), bwh[(b0 + 5) * 4], a1); \
    a2 = MFMA(B16(r6), bwh[(b0 + 6) * 4], a2); a3 = MFMA(B16(r7), bwh[(b0 + 7) * 4], a3);

// ---------------------------------------------------------------------------
// Persistent kernel, 64 blocks x 384 threads (6 waves), 1 block/CU.
// Block b owns r/u/cand columns [b*16, b*16+16). Waves: rt = wid&1 (16-row
// batch tile), role = wid>>1: 0 = r-gate (publishes rh), 1 = u-gate (LDS
// handoff + global "h-read-done" flag), 2 = candidate (finalizes/publishes h).
// Full-K per wave: no cross-wave reduction, NO __syncthreads in the loop.
__global__ __launch_bounds__(TPB, 1) void gru_kernel(
    const unsigned short* __restrict__ Xbf,
    const unsigned short* __restrict__ WgT,
    const unsigned short* __restrict__ WcT,
    const float* __restrict__ bg,
    const float* __restrict__ bc,
    float* __restrict__ out,
    unsigned short* __restrict__ hpub,
    unsigned short* __restrict__ rpub,
    int* __restrict__ hflag,     // [64] x 16B : h generation (wave_c)
    int* __restrict__ fpair)     // [64] x 16B : {rh gen (wave_r), h-read-done (wave_u)}
{
    __shared__ unsigned short sWg[32 * PK];        // 98,816 B
    __shared__ unsigned short sWc[16 * PK];        // 49,408 B
    __shared__ float uLds[2][16][17];              //  2,176 B (u handoff)
    __shared__ float hpLds[2][16][17];             //  2,176 B (h_prev handoff)
    __shared__ unsigned short stage[2][2][16][16]; //  2,048 B (publish transpose)
    __shared__ int lflag[2][2][16];                //    512 B ([rt][0]=u, [rt][1]=hp)
                                                   // total 155,136 B

    const int b    = blockIdx.x;
    const int tid  = threadIdx.x;
    const int wid  = tid >> 6;
    const int lane = tid & 63;
    const int l15  = lane & 15;
    const int lq   = lane >> 4;
    const int rt   = wid & 1;
    const int role = wid >> 1;                     // 0=r 1=u 2=c
    const int arow = rt * 16 + l15;                // A-fragment row
    const int bcol0= b * 16;

    // ---- stage weight slices into LDS + zero LDS flags (once) ----
    {
        s8v* dst = (s8v*)sWg;
        for (int idx = tid; idx < 32 * K8; idx += TPB) {
            int c = idx / K8, k8 = idx % K8;
            int gc = (c < 16) ? (bcol0 + c) : (HH + bcol0 + (c - 16));
            dst[c * PK8 + k8] = ((const s8v*)(WgT + (size_t)gc * KK))[k8];
        }
        s8v* dst2 = (s8v*)sWc;
        for (int idx = tid; idx < 16 * K8; idx += TPB) {
            int c = idx / K8, k8 = idx % K8;
            dst2[c * PK8 + k8] = ((const s8v*)(WcT + (size_t)(bcol0 + c) * KK))[k8];
        }
        if (tid < 4) lflag[tid >> 1][tid & 1][0] = 0;
    }

    const s8v* sWg8 = (const s8v*)sWg;
    const s8v* sWc8 = (const s8v*)sWc;
    const s8v* bw = (role == 0) ? (sWg8 + l15 * PK8 + lq)
                  : (role == 1) ? (sWg8 + (16 + l15) * PK8 + lq)
                                : (sWc8 + l15 * PK8 + lq);
    const s8v* bwx = bw;                 // x k-chunks at bwx[c*4], c=0..15
    const s8v* bwh = bw + DD / 8;        // h k-chunks at bwh[j*4], j=0..31
    const float bias = (role == 0) ? bg[bcol0 + l15]
                     : (role == 1) ? bg[HH + bcol0 + l15]
                                   : bc[bcol0 + l15];

    const unsigned short* srcbuf = (role == 2) ? rpub : hpub;
    volatile int* myUflag  = &lflag[rt][0][0];
    volatile int* myHpflag = &lflag[rt][1][0];

    float hprevC[4] = {0.f, 0.f, 0.f, 0.f};   // wave_c's own h state

    __syncthreads();   // weights + flags ready; the ONLY block barrier

#pragma unroll 1
    for (int t = 0; t < TT; ++t) {
        const s8v* xp = (const s8v*)(Xbf + (size_t)arow * (TT * DD) + (size_t)t * DD) + lq;

        // ---- x-part: full 16 chunks, 4 accumulators (pre-poll slack work) ----
        f4v a0 = {0,0,0,0}, a1 = {0,0,0,0}, a2 = {0,0,0,0}, a3 = {0,0,0,0};
#pragma unroll
        for (int c = 0; c < 16; c += 4) {
            a0 = MFMA(xp[(c + 0) * 4], bwx[(c + 0) * 4], a0);
            a1 = MFMA(xp[(c + 1) * 4], bwx[(c + 1) * 4], a1);
            a2 = MFMA(xp[(c + 2) * 4], bwx[(c + 2) * 4], a2);
            a3 = MFMA(xp[(c + 3) * 4], bwx[(c + 3) * 4], a3);
        }

        // ---- recurrent part: poll own producer set, rolling loads, 32 MFMAs ----
        if (t > 0) {
            if (role == 2) poll2(fpair, t, lane);     // rh_t ready AND all h-reads done
            else           poll1(hflag, t, lane);     // h_{t-1} ready
            const unsigned short* src = srcbuf + (size_t)arow * HH + lq * 8;
            u4v h0, h1, h2, h3, h4, h5, h6, h7, h8, h9, hA, hB, hC, hD, hE, hF;
            h0 = cload16(src);       h1 = cload16(src + 32);  h2 = cload16(src + 64);  h3 = cload16(src + 96);
            h4 = cload16(src + 128); h5 = cload16(src + 160); h6 = cload16(src + 192); h7 = cload16(src + 224);
            h8 = cload16(src + 256); h9 = cload16(src + 288); hA = cload16(src + 320); hB = cload16(src + 352);
            hC = cload16(src + 384); hD = cload16(src + 416); hE = cload16(src + 448); hF = cload16(src + 480);
            WAIT_VM(8);
            C8(0, h0, h1, h2, h3, h4, h5, h6, h7)
            h0 = cload16(src + 512); h1 = cload16(src + 544); h2 = cload16(src + 576); h3 = cload16(src + 608);
            h4 = cload16(src + 640); h5 = cload16(src + 672); h6 = cload16(src + 704); h7 = cload16(src + 736);
            WAIT_VM(8);
            C8(8, h8, h9, hA, hB, hC, hD, hE, hF)
            h8 = cload16(src + 768); h9 = cload16(src + 800); hA = cload16(src + 832); hB = cload16(src + 864);
            hC = cload16(src + 896); hD = cload16(src + 928); hE = cload16(src + 960); hF = cload16(src + 992);
            WAIT_VM(8);
            C8(16, h0, h1, h2, h3, h4, h5, h6, h7)
            WAIT_VM(0);
            // all h loads retired: wave_u certifies h_{t-1} consumed (off-chain)
            if (role == 1 && lane == 0) cstore4(fpair + b * 4 + 1, t);
            C8(24, h8, h9, hA, hB, hC, hD, hE, hF)
        }

        float z[4];
#pragma unroll
        for (int i = 0; i < 4; ++i) z[i] = (a0[i] + a1[i]) + (a2[i] + a3[i]) + bias;

        // ---- role-specific finalize ----
        if (role == 0) {
            // r-gate -> rh publish (needs h_prev from wave_c, written step t-1)
            if (t > 0) {
                lds_spin(myHpflag, t);
#pragma unroll
                for (int i = 0; i < 4; ++i) {
                    float r = 1.f / (1.f + __expf(-z[i]));
                    float rh = r * hpLds[rt][lq * 4 + i][l15];
                    __hip_bfloat16 hb16 = __float2bfloat16(rh);
                    stage[rt][0][lq * 4 + i][l15] = *(unsigned short*)&hb16;
                }
                int prow = lane >> 2, pch = (lane & 3) * 4;
                u2v v = *reinterpret_cast<const u2v*>(&stage[rt][0][prow][pch]);
                cstore8(rpub + (size_t)(rt * 16 + prow) * HH + bcol0 + pch, v);
                asm volatile("s_waitcnt vmcnt(0)" ::: "memory");
                if (lane == 0) cstore4(fpair + b * 4, t);
            }
        } else if (role == 1) {
            // u-gate -> LDS handoff to wave_c
#pragma unroll
            for (int i = 0; i < 4; ++i)
                uLds[rt][lq * 4 + i][l15] = 1.f / (1.f + __expf(-z[i]));
            lds_set(myUflag, t + 1, lane);
        } else {
            // candidate -> h update, publish, handoffs
            lds_spin(myUflag, t + 1);
            float hn[4];
#pragma unroll
            for (int i = 0; i < 4; ++i) {
                float e = __expf(2.f * z[i]);
                float cv = 1.f - 2.f / (e + 1.f);
                float u = uLds[rt][lq * 4 + i][l15];
                hn[i] = u * hprevC[i] + (1.f - u) * cv;
                hprevC[i] = hn[i];
                __hip_bfloat16 hb16 = __float2bfloat16(hn[i]);
                stage[rt][1][lq * 4 + i][l15] = *(unsigned short*)&hb16;
            }
            int prow = lane >> 2, pch = (lane & 3) * 4;
            u2v v = *reinterpret_cast<const u2v*>(&stage[rt][1][prow][pch]);
            cstore8(hpub + (size_t)(rt * 16 + prow) * HH + bcol0 + pch, v);
            asm volatile("s_waitcnt vmcnt(0)" ::: "memory");
            if (lane == 0) cstore4(hflag + b * 4, t + 1);
            // off-chain: h_prev handoff to wave_r, then out stores
#pragma unroll
            for (int i = 0; i < 4; ++i) hpLds[rt][lq * 4 + i][l15] = hn[i];
            lds_set(myHpflag, t + 1, lane);
#pragma unroll
            for (int i = 0; i < 4; ++i)
                out[(size_t)(rt * 16 + lq * 4 + i) * (TT * HH) + (size_t)t * HH + bcol0 + l15] = hn[i];
        }
    }
}

// ---------------------------------------------------------------------------
extern "C" void kernel_launch(void* const* d_in, const int* in_sizes, int n_in,
                              void* d_out, int out_size, void* d_ws, size_t ws_size,
                              hipStream_t stream) {
    const float* X  = (const float*)d_in[0];
    const float* gk = (const float*)d_in[1];
    const float* gb = (const float*)d_in[2];
    const float* ck = (const float*)d_in[3];
    const float* cb = (const float*)d_in[4];
    float* out = (float*)d_out;
    char* ws = (char*)d_ws;
    if (ws_size < OFF_FLG + SZ_FLG) return;

    unsigned short* WgT  = (unsigned short*)(ws + OFF_WGT);
    unsigned short* WcT  = (unsigned short*)(ws + OFF_WCT);
    unsigned short* Xbf  = (unsigned short*)(ws + OFF_XBF);
    unsigned short* hpub = (unsigned short*)(ws + OFF_HPB);
    unsigned short* rpub = (unsigned short*)(ws + OFF_RPB);
    int*            hflag = (int*)(ws + OFF_FLG);
    int*            fpair = hflag + NBLK * 4;

    hipMemsetAsync(hflag, 0, SZ_FLG, stream);

    dim3 tb(256);
    wtr_kernel<<<dim3(2 * HH / 32, KK / 32), tb, 0, stream>>>(gk, WgT, 2 * HH);
    wtr_kernel<<<dim3(HH / 32, KK / 32), tb, 0, stream>>>(ck, WcT, HH);
    xconv_kernel<<<(BB * TT * DD) / (256 * 4), tb, 0, stream>>>(X, Xbf);

    gru_kernel<<<NBLK, dim3(TPB), 0, stream>>>(Xbf, WgT, WcT, gb, cb, out,
                                               hpub, rpub, hflag, fpair);
}

// Round 13
// 5151.334 us; speedup vs baseline: 1.2952x; 1.2952x over previous
//
#include <hip/hip_runtime.h>
#include <hip/hip_bf16.h>

typedef short s8v __attribute__((ext_vector_type(8)));
typedef float f4v __attribute__((ext_vector_type(4)));
typedef unsigned int u4v __attribute__((ext_vector_type(4)));
typedef unsigned int u2v __attribute__((ext_vector_type(2)));

#define NBLK 64
#define TPB 512

constexpr int BB = 32, TT = 512, DD = 512, HH = 1024;
constexpr int KK = DD + HH;          // 1536
constexpr int PK = KK + 8;           // padded LDS K-stride
constexpr int PK8 = PK / 8;
constexpr int K8 = KK / 8;
constexpr size_t BBHH = (size_t)BB * HH;       // elements per publish slot

// ---- workspace layout (bytes) ----
constexpr size_t OFF_WGT = 0;
constexpr size_t SZ_WGT  = (size_t)2 * HH * KK * 2;
constexpr size_t OFF_WCT = OFF_WGT + SZ_WGT;
constexpr size_t SZ_WCT  = (size_t)HH * KK * 2;
constexpr size_t OFF_XBF = OFF_WCT + SZ_WCT;
constexpr size_t SZ_XBF  = (size_t)BB * TT * DD * 2;
constexpr size_t OFF_HPB = OFF_XBF + SZ_XBF;                    // h publish, T-deep
constexpr size_t SZ_PUBT = BBHH * 2 * TT;                       // 33,554,432
constexpr size_t OFF_RPB = OFF_HPB + SZ_PUBT;                   // rh publish, T-deep
constexpr size_t NEED    = OFF_RPB + SZ_PUBT;                   // ~93.3 MB (fits: r10 ran deep)

// ---------------------------------------------------------------------------
__global__ void wtr_kernel(const float* __restrict__ in, unsigned short* __restrict__ out, int N) {
    __shared__ float tl[32][33];
    int tx = threadIdx.x & 31, ty = threadIdx.x >> 5;
    int n0 = blockIdx.x * 32, k0 = blockIdx.y * 32;
#pragma unroll
    for (int r = ty; r < 32; r += 8) tl[r][tx] = in[(size_t)(k0 + r) * N + n0 + tx];
    __syncthreads();
#pragma unroll
    for (int r = ty; r < 32; r += 8) {
        __hip_bfloat16 h = __float2bfloat16(tl[tx][r]);
        out[(size_t)(n0 + r) * KK + k0 + tx] = *reinterpret_cast<unsigned short*>(&h);
    }
}

__global__ void xconv_kernel(const float* __restrict__ X, unsigned short* __restrict__ Xbf) {
    size_t i = ((size_t)blockIdx.x * 256 + threadIdx.x) * 4;
    float4 v = *reinterpret_cast<const float4*>(X + i);
    __hip_bfloat16 h0 = __float2bfloat16(v.x), h1 = __float2bfloat16(v.y);
    __hip_bfloat16 h2 = __float2bfloat16(v.z), h3 = __float2bfloat16(v.w);
    ushort4 o;
    o.x = *(unsigned short*)&h0; o.y = *(unsigned short*)&h1;
    o.z = *(unsigned short*)&h2; o.w = *(unsigned short*)&h3;
    *reinterpret_cast<ushort4*>(Xbf + i) = o;
}

// ---------------------------------------------------------------------------
// Coherent primitives (sc0 sc1 = system scope, proven r2-r11). The POISON
// protocol replaces flags: publish slots are write-once per launch, poisoned
// to 0xFF (bf16 NaN) by a memset; consumers re-load any dword still equal to
// 0xFFFFFFFF. Legit data (sigmoid/tanh-mix outputs, finite & bounded) can
// never be NaN, so the check is exact. Per-dword checks make partial-line
// landing safe (dword writes are atomic at the coherence point).
__device__ __forceinline__ u4v cload16(const void* p) {
    u4v r; asm volatile("global_load_dwordx4 %0, %1, off sc0 sc1" : "=v"(r) : "v"(p) : "memory"); return r;
}
__device__ __forceinline__ void cstore8(void* p, u2v v) {
    asm volatile("global_store_dwordx2 %0, %1, off sc0 sc1" :: "v"(p), "v"(v) : "memory");
}
#define B16(x) __builtin_bit_cast(s8v, (x))
#define WAIT_VM(n) do { asm volatile("s_waitcnt vmcnt(" #n ")" ::: "memory"); \
                        __builtin_amdgcn_sched_barrier(0); } while (0)

__device__ __forceinline__ int dirty16(u4v v) {
    return (v[0] == 0xFFFFFFFFu) | (v[1] == 0xFFFFFFFFu) |
           (v[2] == 0xFFFFFFFFu) | (v[3] == 0xFFFFFFFFu);
}

#define MFMA(A, B, C) __builtin_amdgcn_mfma_f32_16x16x32_bf16((A), (B), (C), 0, 0, 0)

// ---------------------------------------------------------------------------
// Persistent kernel, 64 blocks x 512 threads (8 waves), 1 block/CU.
// Block b owns r/u/cand columns [b*16, b*16+16).
// Waves: ks = wid>>1 (4-way K-split), rt = wid&1 (16-row batch tile).
// Rendezvous = poison-validated data only: no flags, no drains, no polls.
__global__ __launch_bounds__(TPB, 1) void gru_kernel(
    const unsigned short* __restrict__ Xbf,
    const unsigned short* __restrict__ WgT,
    const unsigned short* __restrict__ WcT,
    const float* __restrict__ bg,
    const float* __restrict__ bc,
    float* __restrict__ out,
    unsigned short* __restrict__ hpub,
    unsigned short* __restrict__ rpub)
{
    __shared__ unsigned short sWg[32 * PK];        // 98,816 B
    __shared__ unsigned short sWc[16 * PK];        // 49,408 B
    __shared__ float sP[3][2][2][16][16];          // 12,288 B
    __shared__ unsigned short sStage[2][16][16];   //  1,024 B (per-rt transpose stage)

    const int b    = blockIdx.x;
    const int tid  = threadIdx.x;
    const int wid  = tid >> 6;
    const int lane = tid & 63;
    const int l15  = lane & 15;
    const int lq   = lane >> 4;
    const int ks   = wid >> 1;
    const int rt   = wid & 1;
    const int roff = rt * 16;
    const int arow = roff + l15;
    const int bcol0= b * 16;

    // ---- stage weight slices into LDS (once) ----
    {
        s8v* dst = (s8v*)sWg;
        for (int idx = tid; idx < 32 * K8; idx += TPB) {
            int c = idx / K8, k8 = idx % K8;
            int gc = (c < 16) ? (bcol0 + c) : (HH + bcol0 + (c - 16));
            dst[c * PK8 + k8] = ((const s8v*)(WgT + (size_t)gc * KK))[k8];
        }
        s8v* dst2 = (s8v*)sWc;
        for (int idx = tid; idx < 16 * K8; idx += TPB) {
            int c = idx / K8, k8 = idx % K8;
            dst2[c * PK8 + k8] = ((const s8v*)(WcT + (size_t)(bcol0 + c) * KK))[k8];
        }
    }

    const float bgr  = bg[bcol0 + l15];
    const float bgu  = bg[HH + bcol0 + l15];
    const float bcv  = bc[bcol0 + l15];
    const int   ccol = bcol0 + l15;

    const s8v* sWg8 = (const s8v*)sWg;
    const s8v* sWc8 = (const s8v*)sWc;
    const s8v* bwr = sWg8 + l15 * PK8 + lq;          // r-col weights
    const s8v* bwu = sWg8 + (16 + l15) * PK8 + lq;   // u-col weights
    const s8v* bwc = sWc8 + l15 * PK8 + lq;          // cand weights
    const s8v* bwrx = bwr + 16 * ks;                 // x chunks [4ks..4ks+4)
    const s8v* bwux = bwu + 16 * ks;
    const s8v* bwrh = bwr + 64 + 32 * ks;            // h chunks [8ks..8ks+8)
    const s8v* bwuh = bwu + 64 + 32 * ks;
    const s8v* bwcx = bwc + 16 * ks;
    const s8v* bwch = bwc + 64 + 32 * ks;

    float hprev[4] = {0.f, 0.f, 0.f, 0.f};   // valid in ks==0 waves
    float ureg[4]  = {0.f, 0.f, 0.f, 0.f};

    __syncthreads();

#pragma unroll 1
    for (int t = 0; t < TT; ++t) {
        const s8v* xk = (const s8v*)(Xbf + (size_t)arow * (TT * DD) + (size_t)t * DD) + lq + 16 * ks;
        s8v x0 = xk[0], x1 = xk[4], x2 = xk[8], x3 = xk[12];   // shared by A & B

        // ========== Phase A: issue h loads -> x-MFMAs in shadow -> validate ==========
        f4v ar0 = {0,0,0,0}, ar1 = {0,0,0,0}, au0 = {0,0,0,0}, au1 = {0,0,0,0};
        if (t > 0) {
            const unsigned short* hp = hpub + (size_t)(t - 1) * BBHH
                                     + (size_t)arow * HH + ks * 256 + lq * 8;
            u4v hb[8];
#pragma unroll
            for (int j = 0; j < 8; ++j) hb[j] = cload16(hp + (size_t)j * 32);
            ar0 = MFMA(x0, bwrx[0],  ar0); au0 = MFMA(x0, bwux[0],  au0);
            ar1 = MFMA(x1, bwrx[4],  ar1); au1 = MFMA(x1, bwux[4],  au1);
            ar0 = MFMA(x2, bwrx[8],  ar0); au0 = MFMA(x2, bwux[8],  au0);
            ar1 = MFMA(x3, bwrx[12], ar1); au1 = MFMA(x3, bwux[12], au1);
            WAIT_VM(0);
#pragma unroll
            for (int j = 0; j < 8; ++j) {
                while (__builtin_expect(dirty16(hb[j]), 0)) {
                    hb[j] = cload16(hp + (size_t)j * 32);
                    asm volatile("s_waitcnt vmcnt(0)" ::: "memory");
                }
            }
            ar0 = MFMA(B16(hb[0]), bwrh[0],  ar0); au0 = MFMA(B16(hb[0]), bwuh[0],  au0);
            ar1 = MFMA(B16(hb[1]), bwrh[4],  ar1); au1 = MFMA(B16(hb[1]), bwuh[4],  au1);
            ar0 = MFMA(B16(hb[2]), bwrh[8],  ar0); au0 = MFMA(B16(hb[2]), bwuh[8],  au0);
            ar1 = MFMA(B16(hb[3]), bwrh[12], ar1); au1 = MFMA(B16(hb[3]), bwuh[12], au1);
            ar0 = MFMA(B16(hb[4]), bwrh[16], ar0); au0 = MFMA(B16(hb[4]), bwuh[16], au0);
            ar1 = MFMA(B16(hb[5]), bwrh[20], ar1); au1 = MFMA(B16(hb[5]), bwuh[20], au1);
            ar0 = MFMA(B16(hb[6]), bwrh[24], ar0); au0 = MFMA(B16(hb[6]), bwuh[24], au0);
            ar1 = MFMA(B16(hb[7]), bwrh[28], ar1); au1 = MFMA(B16(hb[7]), bwuh[28], au1);
        } else {
            ar0 = MFMA(x0, bwrx[0],  ar0); au0 = MFMA(x0, bwux[0],  au0);
            ar1 = MFMA(x1, bwrx[4],  ar1); au1 = MFMA(x1, bwux[4],  au1);
            ar0 = MFMA(x2, bwrx[8],  ar0); au0 = MFMA(x2, bwux[8],  au0);
            ar1 = MFMA(x3, bwrx[12], ar1); au1 = MFMA(x3, bwux[12], au1);
        }

        // ---- cross-wave K-reduction ----
        f4v pr = ar0 + ar1, pu = au0 + au1;
        if (ks > 0) {
#pragma unroll
            for (int i = 0; i < 4; ++i) {
                sP[ks - 1][rt][0][lq * 4 + i][l15] = pr[i];
                sP[ks - 1][rt][1][lq * 4 + i][l15] = pu[i];
            }
        }
        __syncthreads();                             // S1: A partials ready
        float zr[4], zu[4];
        if (ks == 0) {
#pragma unroll
            for (int i = 0; i < 4; ++i) {
                int rr = lq * 4 + i;
                zr[i] = pr[i] + sP[0][rt][0][rr][l15] + sP[1][rt][0][rr][l15]
                              + sP[2][rt][0][rr][l15] + bgr;
                zu[i] = pu[i] + sP[0][rt][1][rr][l15] + sP[1][rt][1][rr][l15]
                              + sP[2][rt][1][rr][l15] + bgu;
            }
        }
        __syncthreads();                             // S2: sP free for phase B
        if (ks == 0) {
#pragma unroll
            for (int i = 0; i < 4; ++i) {
                float r = 1.f / (1.f + __expf(-zr[i]));
                ureg[i] = 1.f / (1.f + __expf(-zu[i]));
                __hip_bfloat16 hb16 = __float2bfloat16(r * hprev[i]);
                sStage[rt][lq * 4 + i][l15] = *(unsigned short*)&hb16;
            }
            if (t > 0) {                             // rh slot 0 never read
                int prow = lane >> 2, pc4 = (lane & 3) * 4;
                u2v v = *reinterpret_cast<const u2v*>(&sStage[rt][prow][pc4]);  // same-wave LDS
                cstore8(rpub + (size_t)t * BBHH + (size_t)(roff + prow) * HH + bcol0 + pc4, v);
                // no drain, no flag — data self-validates at the consumer
            }
        }

        // ========== Phase B: issue rh loads -> x-MFMAs in shadow -> validate ==========
        f4v c0 = {0,0,0,0}, c1 = {0,0,0,0};
        if (t > 0) {
            const unsigned short* rp = rpub + (size_t)t * BBHH
                                     + (size_t)arow * HH + ks * 256 + lq * 8;
            u4v rb[8];
#pragma unroll
            for (int j = 0; j < 8; ++j) rb[j] = cload16(rp + (size_t)j * 32);
            c0 = MFMA(x0, bwcx[0],  c0); c1 = MFMA(x1, bwcx[4],  c1);
            c0 = MFMA(x2, bwcx[8],  c0); c1 = MFMA(x3, bwcx[12], c1);
            WAIT_VM(0);
#pragma unroll
            for (int j = 0; j < 8; ++j) {
                while (__builtin_expect(dirty16(rb[j]), 0)) {
                    rb[j] = cload16(rp + (size_t)j * 32);
                    asm volatile("s_waitcnt vmcnt(0)" ::: "memory");
                }
            }
            c0 = MFMA(B16(rb[0]), bwch[0],  c0); c1 = MFMA(B16(rb[1]), bwch[4],  c1);
            c0 = MFMA(B16(rb[2]), bwch[8],  c0); c1 = MFMA(B16(rb[3]), bwch[12], c1);
            c0 = MFMA(B16(rb[4]), bwch[16], c0); c1 = MFMA(B16(rb[5]), bwch[20], c1);
            c0 = MFMA(B16(rb[6]), bwch[24], c0); c1 = MFMA(B16(rb[7]), bwch[28], c1);
        } else {
            c0 = MFMA(x0, bwcx[0],  c0); c1 = MFMA(x1, bwcx[4],  c1);
            c0 = MFMA(x2, bwcx[8],  c0); c1 = MFMA(x3, bwcx[12], c1);
        }

        f4v pc = c0 + c1;
        if (ks > 0) {
#pragma unroll
            for (int i = 0; i < 4; ++i) sP[ks - 1][rt][0][lq * 4 + i][l15] = pc[i];
        }
        __syncthreads();                             // S3: B partials ready
        float zc[4];
        if (ks == 0) {
#pragma unroll
            for (int i = 0; i < 4; ++i) {
                int rr = lq * 4 + i;
                zc[i] = pc[i] + sP[0][rt][0][rr][l15] + sP[1][rt][0][rr][l15]
                              + sP[2][rt][0][rr][l15] + bcv;
            }
        }
        __syncthreads();                             // S4: sP free for next step
        if (ks == 0) {
#pragma unroll
            for (int i = 0; i < 4; ++i) {
                float e = __expf(2.f * zc[i]);
                float cv = 1.f - 2.f / (e + 1.f);
                float hn = ureg[i] * hprev[i] + (1.f - ureg[i]) * cv;
                hprev[i] = hn;
                __hip_bfloat16 hb16 = __float2bfloat16(hn);
                sStage[rt][lq * 4 + i][l15] = *(unsigned short*)&hb16;
            }
            int prow = lane >> 2, pc4 = (lane & 3) * 4;
            u2v v = *reinterpret_cast<const u2v*>(&sStage[rt][prow][pc4]);      // same-wave LDS
            cstore8(hpub + (size_t)t * BBHH + (size_t)(roff + prow) * HH + bcol0 + pc4, v);
            // out stores — off the rendezvous critical path
#pragma unroll
            for (int i = 0; i < 4; ++i) {
                int row = roff + lq * 4 + i;
                out[(size_t)row * (TT * HH) + (size_t)t * HH + ccol] = hprev[i];
            }
        }
    }
}

// ---------------------------------------------------------------------------
extern "C" void kernel_launch(void* const* d_in, const int* in_sizes, int n_in,
                              void* d_out, int out_size, void* d_ws, size_t ws_size,
                              hipStream_t stream) {
    const float* X  = (const float*)d_in[0];
    const float* gk = (const float*)d_in[1];
    const float* gb = (const float*)d_in[2];
    const float* ck = (const float*)d_in[3];
    const float* cb = (const float*)d_in[4];
    float* out = (float*)d_out;
    char* ws = (char*)d_ws;
    if (ws_size < NEED) return;   // r10 confirmed ws fits the T-deep layout

    unsigned short* WgT  = (unsigned short*)(ws + OFF_WGT);
    unsigned short* WcT  = (unsigned short*)(ws + OFF_WCT);
    unsigned short* Xbf  = (unsigned short*)(ws + OFF_XBF);
    unsigned short* hpub = (unsigned short*)(ws + OFF_HPB);
    unsigned short* rpub = (unsigned short*)(ws + OFF_RPB);

    // Re-poison the write-once publish slots every launch (graph-replay safe).
    hipMemsetAsync(hpub, 0xFF, 2 * SZ_PUBT, stream);

    dim3 tb(256);
    wtr_kernel<<<dim3(2 * HH / 32, KK / 32), tb, 0, stream>>>(gk, WgT, 2 * HH);
    wtr_kernel<<<dim3(HH / 32, KK / 32), tb, 0, stream>>>(ck, WcT, HH);
    xconv_kernel<<<(BB * TT * DD) / (256 * 4), tb, 0, stream>>>(X, Xbf);

    gru_kernel<<<NBLK, dim3(TPB), 0, stream>>>(Xbf, WgT, WcT, gb, cb, out,
                                               hpub, rpub);
}